// Round 1
// baseline (68.008 us; speedup 1.0000x reference)
//
#include <hip/hip_runtime.h>

#define BPB       16          // batch elements per block
#define NTHREADS  256
#define B_TOTAL   65536
#define IN_PER_B  270         // 9 rows * 30
#define OUT_PER_B 648         // 6 * 36 * 3
#define NWIN      27          // 9 rows * 3 windows
#define NPAIRQ    108         // 36 pairs * 3 windows

// triu_indices(9, k=1)
__constant__ int c_I[36] = {0,0,0,0,0,0,0,0, 1,1,1,1,1,1,1, 2,2,2,2,2,2,
                            3,3,3,3,3, 4,4,4,4, 5,5,5, 6,6, 7};
__constant__ int c_J[36] = {1,2,3,4,5,6,7,8, 2,3,4,5,6,7,8, 3,4,5,6,7,8,
                            4,5,6,7,8, 5,6,7,8, 6,7,8, 7,8, 8};

__global__ __launch_bounds__(NTHREADS) void feature_catch_kernel(
    const float* __restrict__ x, float* __restrict__ out)
{
    __shared__ __align__(16) float xin[BPB * IN_PER_B];   // staged input
    __shared__ float s1[BPB * NWIN];                      // window sums
    __shared__ float s2[BPB * NWIN];                      // window sum-sq
    __shared__ float sdl[BPB * NWIN];                     // decay dot
    __shared__ float pv[BPB * NPAIRQ];                    // p-values

    const int tid = threadIdx.x;
    const int blk = blockIdx.x;

    // ---- Phase 1: coalesced global -> LDS (float4) ----
    {
        const float4* xg4 = (const float4*)(x + (size_t)blk * (BPB * IN_PER_B));
        float4* xin4 = (float4*)xin;
        #pragma unroll
        for (int i = tid; i < BPB * IN_PER_B / 4; i += NTHREADS)
            xin4[i] = xg4[i];
    }
    __syncthreads();

    // ---- Phase 2: per-window stats (sum, sumsq, decay-dot) ----
    for (int i = tid; i < BPB * NWIN; i += NTHREADS) {
        const float* w = &xin[(i / NWIN) * IN_PER_B + (i % NWIN) * 10];
        float a = 0.f, b = 0.f, c = 0.f;
        #pragma unroll
        for (int d = 0; d < 10; ++d) {
            float v = w[d];
            a += v;
            b += v * v;
            c += v * ((float)(10 - d) * (1.0f / 55.0f));
        }
        s1[i] = a; s2[i] = b; sdl[i] = c;
    }
    __syncthreads();

    // ---- Phase 2b: pair correlations -> p-value (closed-form betainc) ----
    // I_x(4, 0.5) with x = clip(1-r^2,0,1), s = |r|:
    //   p = 1 - (35/16) * (s - s^3 + 0.6 s^5 - s^7/7)
    for (int i = tid; i < BPB * NPAIRQ; i += NTHREADS) {
        const int b  = i / NPAIRQ;
        const int q  = i % NPAIRQ;       // q = pair*3 + n (matches output order)
        const int pr = q / 3;
        const int n  = q % 3;
        const int wi = c_I[pr] * 3 + n;
        const int wj = c_J[pr] * 3 + n;
        const float* xi = &xin[b * IN_PER_B + wi * 10];
        const float* xj = &xin[b * IN_PER_B + wj * 10];
        float cross = 0.f;
        #pragma unroll
        for (int d = 0; d < 10; ++d) cross += xi[d] * xj[d];
        const float S1i = s1[b * NWIN + wi], S1j = s1[b * NWIN + wj];
        const float num = cross - S1i * S1j * 0.1f;
        const float cci = s2[b * NWIN + wi] - S1i * S1i * 0.1f;
        const float ccj = s2[b * NWIN + wj] - S1j * S1j * 0.1f;
        const float r   = num * rsqrtf(cci * ccj);
        const float s   = fminf(fabsf(r), 1.0f);
        const float ss  = s * s;
        const float F   = s * (1.0f + ss * (-1.0f + ss * (0.6f - ss * (1.0f / 7.0f))));
        pv[i] = 1.0f - 2.1875f * F;
    }
    __syncthreads();

    // ---- Phase 3: output-mapped coalesced float4 stores ----
    // out layout per b: [c=0..5][pair=0..35][n=0..2]
    {
        float4* out4 = (float4*)(out + (size_t)blk * (BPB * OUT_PER_B));
        for (int i4 = tid; i4 < BPB * OUT_PER_B / 4; i4 += NTHREADS) {
            float4 v;
            #pragma unroll
            for (int e = 0; e < 4; ++e) {
                const int i   = i4 * 4 + e;
                const int bl  = i / OUT_PER_B;
                const int rem = i % OUT_PER_B;
                const int c   = rem / NPAIRQ;
                const int q   = rem % NPAIRQ;
                float val;
                if (c < 2) {
                    val = pv[bl * NPAIRQ + q];          // conv1 == conv2
                } else {
                    const int p = q / 3, n = q % 3;
                    if (p >= 9) {
                        val = 0.0f;                     // zero padding
                    } else {
                        const int w  = bl * NWIN + p * 3 + n;
                        const float S1 = s1[w];
                        if (c == 4)      val = S1;      // ret = sum
                        else if (c == 5) val = sdl[w];  // decay dot
                        else {
                            const float cc  = s2[w] - S1 * S1 * 0.1f;
                            const float std = sqrtf(cc * 0.1f);
                            val = (c == 2) ? std : (S1 * 0.1f) / std;  // std / zscore
                        }
                    }
                }
                (&v.x)[e] = val;
            }
            out4[i4] = v;
        }
    }
}

extern "C" void kernel_launch(void* const* d_in, const int* in_sizes, int n_in,
                              void* d_out, int out_size, void* d_ws, size_t ws_size,
                              hipStream_t stream) {
    const float* x = (const float*)d_in[0];
    float* out = (float*)d_out;
    dim3 grid(B_TOTAL / BPB);   // 4096 blocks
    feature_catch_kernel<<<grid, NTHREADS, 0, stream>>>(x, out);
}

// Round 2
// 40.994 us; speedup vs baseline: 1.6590x; 1.6590x over previous
//
#include <hip/hip_runtime.h>

#define BPB       8           // batch elements per block
#define NTHREADS  256
#define B_TOTAL   65536
#define IN_PER_B  270         // 9 rows * 30
#define OUT_PER_B 648         // 6 * 36 * 3
#define NWIN      27          // 9 rows * 3 windows
#define NPAIRQ    108         // 36 pairs * 3 windows

// triu_indices(9, k=1), packed (I<<8)|J
__constant__ unsigned int c_IJ[36] = {
    0x0001,0x0002,0x0003,0x0004,0x0005,0x0006,0x0007,0x0008,
    0x0102,0x0103,0x0104,0x0105,0x0106,0x0107,0x0108,
    0x0203,0x0204,0x0205,0x0206,0x0207,0x0208,
    0x0304,0x0305,0x0306,0x0307,0x0308,
    0x0405,0x0406,0x0407,0x0408,
    0x0506,0x0507,0x0508,
    0x0607,0x0608,
    0x0708
};

__global__ __launch_bounds__(NTHREADS) void feature_catch_kernel(
    const float* __restrict__ x, float* __restrict__ out)
{
    __shared__ __align__(16) float xin[BPB * IN_PER_B];   // staged input  (8640 B)
    __shared__ float s1[BPB * NWIN];                      // window sums   (864 B)
    __shared__ float sistd[BPB * NWIN];                   // rsqrt(cc)     (864 B)
    __shared__ __align__(16) float feat[BPB * 112];       // 4ch x 28 (std,zs,ret,dl; [27]=0 pad)
    __shared__ __align__(16) float pv[BPB * NPAIRQ];      // p-values      (3456 B)
    __shared__ unsigned int sIJ[36];

    const int tid = threadIdx.x;
    const int blk = blockIdx.x;

    // ---- Phase 1: coalesced global -> LDS (float4) + LUT copy ----
    {
        const float4* xg4 = (const float4*)(x + (size_t)blk * (BPB * IN_PER_B));
        float4* xin4 = (float4*)xin;
        #pragma unroll
        for (int i = tid; i < BPB * IN_PER_B / 4; i += NTHREADS)
            xin4[i] = xg4[i];
        if (tid < 36) sIJ[tid] = c_IJ[tid];
    }
    __syncthreads();

    // ---- Phase 2: per-window stats (one thread per window; 216 < 256) ----
    if (tid < BPB * NWIN) {
        const int b = tid / NWIN, w = tid % NWIN;
        const float2* p = (const float2*)&xin[b * IN_PER_B + w * 10];
        float a = 0.f, sq = 0.f, dl = 0.f;
        #pragma unroll
        for (int d = 0; d < 5; ++d) {
            const float2 v = p[d];
            a  += v.x + v.y;
            sq += v.x * v.x + v.y * v.y;
            dl += v.x * (float)(10 - 2 * d) + v.y * (float)(9 - 2 * d);
        }
        dl *= (1.0f / 55.0f);
        const float cc  = sq - a * a * 0.1f;     // 10 * variance
        const float is  = rsqrtf(cc);
        const float std = cc * is * 0.31622776601683794f;   // sqrt(cc/10)
        const float zs  = a * 0.31622776601683794f * is;    // mean/std
        s1[tid]    = a;
        sistd[tid] = is;
        float* fb = &feat[b * 112 + w];
        fb[0]  = std;
        fb[28] = zs;
        fb[56] = a;      // ret = window sum
        fb[84] = dl;     // decay dot
    } else if (tid >= NTHREADS - 32) {
        const int idx = tid - (NTHREADS - 32);   // 32 = BPB*4 pad entries
        feat[(idx >> 2) * 112 + (idx & 3) * 28 + 27] = 0.f;
    }
    __syncthreads();

    // ---- Phase 2b: pair correlations -> p-value (closed-form betainc) ----
    // I_x(4, 0.5), x = 1-r^2, s = |r|:  p = 1 - (35/16)(s - s^3 + 0.6 s^5 - s^7/7)
    for (int i = tid; i < BPB * NPAIRQ; i += NTHREADS) {
        const int b  = i / NPAIRQ;
        const int q  = i % NPAIRQ;
        const int pr = q / 3;
        const int n  = q - pr * 3;
        const unsigned ij = sIJ[pr];
        const int wi = (int)(ij >> 8) * 3 + n;
        const int wj = (int)(ij & 255u) * 3 + n;
        const float2* pi = (const float2*)&xin[b * IN_PER_B + wi * 10];
        const float2* pj = (const float2*)&xin[b * IN_PER_B + wj * 10];
        float cross = 0.f;
        #pragma unroll
        for (int d = 0; d < 5; ++d) {
            const float2 vi = pi[d], vj = pj[d];
            cross += vi.x * vj.x + vi.y * vj.y;
        }
        const float num = cross - s1[b * NWIN + wi] * s1[b * NWIN + wj] * 0.1f;
        const float r   = num * sistd[b * NWIN + wi] * sistd[b * NWIN + wj];
        const float s   = fminf(fabsf(r), 1.0f);
        const float ss  = s * s;
        const float F   = s * (1.0f + ss * (-1.0f + ss * (0.6f - ss * (1.0f / 7.0f))));
        pv[i] = 1.0f - 2.1875f * F;
    }
    __syncthreads();

    // ---- Phase 3: float4 LDS -> float4 global, uniform-ish branches ----
    // out layout per b: [c=0..5][pair=0..35][n=0..2] = 162 float4
    {
        float4* out4 = (float4*)(out + (size_t)blk * (BPB * OUT_PER_B));
        const float4* pv4   = (const float4*)pv;    // 27 float4 per b
        const float4* feat4 = (const float4*)feat;  // 28 float4 per b (7 per ch)
        for (int i4 = tid; i4 < BPB * 162; i4 += NTHREADS) {
            const int bl  = i4 / 162;
            const int rem = i4 - bl * 162;
            const int c   = rem / 27;
            const int k   = rem - c * 27;
            float4 v;
            if (c < 2)       v = pv4[bl * 27 + k];                  // conv1 == conv2
            else if (k < 7)  v = feat4[bl * 28 + (c - 2) * 7 + k];  // std/zs/ret/dl (+0 pad)
            else             v = make_float4(0.f, 0.f, 0.f, 0.f);   // zero padding
            out4[i4] = v;
        }
    }
}

extern "C" void kernel_launch(void* const* d_in, const int* in_sizes, int n_in,
                              void* d_out, int out_size, void* d_ws, size_t ws_size,
                              hipStream_t stream) {
    const float* x = (const float*)d_in[0];
    float* out = (float*)d_out;
    dim3 grid(B_TOTAL / BPB);   // 8192 blocks
    feature_catch_kernel<<<grid, NTHREADS, 0, stream>>>(x, out);
}

// Round 3
// 40.471 us; speedup vs baseline: 1.6804x; 1.0129x over previous
//
#include <hip/hip_runtime.h>

#define BPB       8           // batch elements per block
#define NTHREADS  256
#define B_TOTAL   65536
#define IN_PER_B  270         // 9 rows * 30
#define OUT_PER_B 648         // 6 * 36 * 3
#define NWIN      27          // 9 rows * 3 windows

// triu_indices(9, k=1), packed (I<<8)|J
__constant__ unsigned int c_IJ[36] = {
    0x0001,0x0002,0x0003,0x0004,0x0005,0x0006,0x0007,0x0008,
    0x0102,0x0103,0x0104,0x0105,0x0106,0x0107,0x0108,
    0x0203,0x0204,0x0205,0x0206,0x0207,0x0208,
    0x0304,0x0305,0x0306,0x0307,0x0308,
    0x0405,0x0406,0x0407,0x0408,
    0x0506,0x0507,0x0508,
    0x0607,0x0608,
    0x0708
};

__global__ __launch_bounds__(NTHREADS) void feature_catch_kernel(
    const float* __restrict__ x, float* __restrict__ out)
{
    __shared__ __align__(16) float xin[BPB * IN_PER_B];   // staged input  (8640 B)
    __shared__ float s1[BPB * NWIN];                      // window sums   (864 B)
    __shared__ float sistd[BPB * NWIN];                   // rsqrt(cc)     (864 B)
    __shared__ __align__(16) float feat[BPB * 112];       // 4ch x 28 (std,zs,ret,dl; [27]=0)
    __shared__ unsigned int sIJ[36];

    const int tid = threadIdx.x;
    const int blk = blockIdx.x;

    // ---- Phase 1: coalesced global -> LDS (float4) + LUT copy ----
    {
        const float4* xg4 = (const float4*)(x + (size_t)blk * (BPB * IN_PER_B));
        float4* xin4 = (float4*)xin;
        #pragma unroll
        for (int i = tid; i < BPB * IN_PER_B / 4; i += NTHREADS)
            xin4[i] = xg4[i];
        if (tid < 36) sIJ[tid] = c_IJ[tid];
    }
    __syncthreads();

    // ---- Phase 2: per-window stats (one thread per window; 216 < 256) ----
    if (tid < BPB * NWIN) {
        const int b = tid / NWIN, w = tid % NWIN;
        const float2* p = (const float2*)&xin[b * IN_PER_B + w * 10];
        float a = 0.f, sq = 0.f, dl = 0.f;
        #pragma unroll
        for (int d = 0; d < 5; ++d) {
            const float2 v = p[d];
            a  += v.x + v.y;
            sq += v.x * v.x + v.y * v.y;
            dl += v.x * (float)(10 - 2 * d) + v.y * (float)(9 - 2 * d);
        }
        dl *= (1.0f / 55.0f);
        const float cc  = sq - a * a * 0.1f;     // 10 * variance
        const float is  = rsqrtf(cc);
        const float std = cc * is * 0.31622776601683794f;   // sqrt(cc/10)
        const float zs  = a * 0.31622776601683794f * is;    // mean/std
        s1[tid]    = a;
        sistd[tid] = is;
        float* fb = &feat[b * 112 + w];
        fb[0]  = std;
        fb[28] = zs;
        fb[56] = a;      // ret = window sum
        fb[84] = dl;     // decay dot
    } else if (tid >= NTHREADS - 32) {
        const int idx = tid - (NTHREADS - 32);   // 32 = BPB*4 pad entries
        feat[(idx >> 2) * 112 + (idx & 3) * 28 + 27] = 0.f;
    }
    __syncthreads();

    // ---- Phase 3 (merged): pair p-values direct to global + feat streaming ----
    float4* out4 = (float4*)out + (size_t)blk * (BPB * OUT_PER_B / 4);

    // 3a: 216 threads each compute 4 consecutive pair-correlations -> one float4,
    //     stored to conv1 and conv2 (identical). Output order q = pair*3 + n.
    if (tid < BPB * 27) {
        const int b = tid / 27, k = tid - (tid / 27) * 27;
        float4 v;
        #pragma unroll
        for (int e = 0; e < 4; ++e) {
            const int q  = k * 4 + e;
            const int pr = q / 3;
            const int n  = q - pr * 3;
            const unsigned ij = sIJ[pr];
            const int wi = (int)(ij >> 8) * 3 + n;
            const int wj = (int)(ij & 255u) * 3 + n;
            const float2* pi = (const float2*)&xin[b * IN_PER_B + wi * 10];
            const float2* pj = (const float2*)&xin[b * IN_PER_B + wj * 10];
            float cross = 0.f;
            #pragma unroll
            for (int d = 0; d < 5; ++d) {
                const float2 vi = pi[d], vj = pj[d];
                cross += vi.x * vj.x + vi.y * vj.y;
            }
            const float num = cross - s1[b * NWIN + wi] * s1[b * NWIN + wj] * 0.1f;
            const float r   = num * sistd[b * NWIN + wi] * sistd[b * NWIN + wj];
            // I_x(4,0.5), x=1-r^2, s=|r|: p = 1 - (35/16)(s - s^3 + 0.6 s^5 - s^7/7)
            const float s   = fminf(fabsf(r), 1.0f);
            const float ss  = s * s;
            const float F   = s * (1.0f + ss * (-1.0f + ss * (0.6f - ss * (1.0f / 7.0f))));
            (&v.x)[e] = 1.0f - 2.1875f * F;
        }
        float4* ob = out4 + b * (OUT_PER_B / 4);
        ob[k]      = v;   // conv1
        ob[27 + k] = v;   // conv2
    }

    // 3b: channels 2..5 (std, zs, ret, dl + zero padding), float4 LDS -> global
    {
        const float4* feat4 = (const float4*)feat;  // 28 float4 per b (7 per ch)
        for (int i4 = tid; i4 < BPB * 108; i4 += NTHREADS) {
            const int bl  = i4 / 108;
            const int rem = i4 - bl * 108;
            const int c   = rem / 27;
            const int k   = rem - c * 27;
            const float4 v = (k < 7) ? feat4[bl * 28 + c * 7 + k]
                                     : make_float4(0.f, 0.f, 0.f, 0.f);
            out4[bl * (OUT_PER_B / 4) + (c + 2) * 27 + k] = v;
        }
    }
}

extern "C" void kernel_launch(void* const* d_in, const int* in_sizes, int n_in,
                              void* d_out, int out_size, void* d_ws, size_t ws_size,
                              hipStream_t stream) {
    const float* x = (const float*)d_in[0];
    float* out = (float*)d_out;
    dim3 grid(B_TOTAL / BPB);   // 8192 blocks
    feature_catch_kernel<<<grid, NTHREADS, 0, stream>>>(x, out);
}